// Round 14
// baseline (94.171 us; speedup 1.0000x reference)
//
#include <hip/hip_runtime.h>
#include <math.h>

#define B_   2
#define S_   2048
#define DIM_ 1024
#define H_   16
#define HD_  64
#define BS_  (B_ * S_)              // 4096
#define BHSD ((size_t)B_ * H_ * S_ * HD_)   // 4M elements
#define CEXP 0.1803368801111244f    // log2(e) / sqrt(64)

typedef unsigned short u16;
typedef unsigned int   u32;
typedef short s16x8 __attribute__((ext_vector_type(8)));
typedef float f32x4 __attribute__((ext_vector_type(4)));
typedef float f32x16 __attribute__((ext_vector_type(16)));

#define MFMA16(a, b, c) __builtin_amdgcn_mfma_f32_16x16x32_bf16((a), (b), (c), 0, 0, 0)
#define MFMA32(a, b, c) __builtin_amdgcn_mfma_f32_32x32x16_bf16((a), (b), (c), 0, 0, 0)

__device__ __forceinline__ u16 f2bf(float f) {
    u32 u = __float_as_uint(f);
    u += 0x7fffu + ((u >> 16) & 1u);            // RNE
    return (u16)(u >> 16);
}
__device__ __forceinline__ float bf2f(u16 h) {
    return __uint_as_float(((u32)h) << 16);
}
__device__ __forceinline__ u32 cvt_pk_bf16(float a, float b) {
    u32 r;
    asm("v_cvt_pk_bf16_f32 %0, %1, %2" : "=v"(r) : "v"(a), "v"(b));
    return r;
}
// async global->LDS, 16B/lane; LDS dest must be WAVE-UNIFORM base (+lane*16)
__device__ __forceinline__ void gl16(void* lds, const void* g) {
    __builtin_amdgcn_global_load_lds(
        (__attribute__((address_space(1))) void*)(g),
        (__attribute__((address_space(3))) void*)(lds), 16, 0, 0);
}

// ---------------------------------------------------------------------------
// prep: fused cvt_x | weight transpose (+q/k col-permutation) | cos/sin table
// | bias concat (permuted). Dispatch by blockIdx.x range.
// ---------------------------------------------------------------------------
__global__ __launch_bounds__(256) void prep(
    const float* __restrict__ x, u16* __restrict__ xb,
    const float* __restrict__ W0, const float* __restrict__ W1,
    const float* __restrict__ W2, const float* __restrict__ W3,
    u16* __restrict__ T0, u16* __restrict__ T1,
    u16* __restrict__ T2, u16* __restrict__ T3,
    const float* __restrict__ bq, const float* __restrict__ bk,
    const float* __restrict__ bv, float* __restrict__ bias3,
    const float* __restrict__ theta, float2* __restrict__ cs)
{
    __shared__ float tile[32][33];
    const int bid = blockIdx.x, tid = threadIdx.x;

    if (bid < 2048) {                       // ---- x -> bf16
        const int i = bid * 256 + tid;
        const float4 a = *(const float4*)(x + (size_t)i * 8);
        const float4 b = *(const float4*)(x + (size_t)i * 8 + 4);
        s16x8 o;
        o[0] = (short)f2bf(a.x); o[1] = (short)f2bf(a.y);
        o[2] = (short)f2bf(a.z); o[3] = (short)f2bf(a.w);
        o[4] = (short)f2bf(b.x); o[5] = (short)f2bf(b.y);
        o[6] = (short)f2bf(b.z); o[7] = (short)f2bf(b.w);
        *(s16x8*)(xb + (size_t)i * 8) = o;
    } else if (bid < 6144) {                // ---- W transpose
        const int idx = bid - 2048;
        const int z = idx >> 10;
        const float* W; u16* T;
        switch (z) {
            case 0: W = W0; T = T0; break;
            case 1: W = W1; T = T1; break;
            case 2: W = W2; T = T2; break;
            default: W = W3; T = T3; break;
        }
        const int n0 = ((idx >> 5) & 31) * 32, k0 = (idx & 31) * 32;
        const int c = tid & 31, rr = tid >> 5;
#pragma unroll
        for (int i = 0; i < 4; ++i) {
            const int k = rr + i * 8;
            tile[k][c] = W[(size_t)(k0 + k) * DIM_ + n0 + c];
        }
        __syncthreads();
#pragma unroll
        for (int i = 0; i < 4; ++i) {
            const int col = n0 + rr + i * 8;
            int pcol = col;
            if (z < 2) {                    // rope col-perm: even->lo, odd->hi
                const int dd = col & 63;
                const int pd = (dd & 1) ? 32 + (dd >> 1) : (dd >> 1);
                pcol = (col & ~63) | pd;
            }
            T[(size_t)pcol * DIM_ + k0 + c] = f2bf(tile[c][rr + i * 8]);
        }
    } else if (bid < 6400) {                // ---- cos/sin table
        const int idx = bid - 6144;
        const int s = idx * 8 + (tid >> 5), j = tid & 31;
        float sn, cn;
        sincosf((float)s * theta[j], &sn, &cn);
        cs[(s << 5) + j] = make_float2(cn, sn);
    } else {                                // ---- bias concat (permuted q,k)
        const int i = (bid - 6400) * 256 + tid;   // 0..3071
        const int which = i >> 10, local = i & 1023;
        const float v = (which == 0) ? bq[local]
                      : (which == 1) ? bk[local] : bv[local];
        int dst = i;
        if (which < 2) {
            const int dd = local & 63;
            const int pd = (dd & 1) ? 32 + (dd >> 1) : (dd >> 1);
            dst = which * 1024 + (local & ~63) + pd;
        }
        bias3[dst] = v;
    }
}

// ---------------------------------------------------------------------------
// bf16 MFMA GEMM, tile 128 x BN, BK=64, 256 threads (4 waves, 2x2 quadrants).
// EPI 0: bf16 head-major out into q|k|VT.
//   q,k: fused RoPE (weights col-permuted; pairs (n, n+2) in-register) +
//        q pre-scaled by log2(e)/8.
//   VT : V transposed with kv bits 2<->3 swapped (MFMA32 PV slot mapping).
// EPI 1: fp32 row-major out.
// ---------------------------------------------------------------------------
template<int BN, int HMIN, int EPI>
__global__ __launch_bounds__(256, 3) void gemm_mfma(
    const u16* __restrict__ A, const u16* __restrict__ Bt,
    const float* __restrict__ bias, void* __restrict__ Yv,
    const float2* __restrict__ cs)
{
    __shared__ u16 As[128 * 64];
    __shared__ u16 Bs[BN * 64];

    const int tid = threadIdx.x, lane = tid & 63, wid = tid >> 6;
    const int l15 = lane & 15, lg = lane >> 4;
    const int row0 = blockIdx.x * 128, col0 = blockIdx.y * BN;
    const int wr = (wid >> 1) * 64;
    const int wc = (wid & 1) * (BN / 2);
    constexpr int NM = 4, NN = BN / 32, BCH = BN / 32;

    const int l8 = lane >> 3, l7 = lane & 7;
    const int colE = ((l7 ^ l8) << 3);          // k-element offset (swizzled)

    const u16* aptr[4]; u16* aldp[4];
#pragma unroll
    for (int i = 0; i < 4; ++i) {
        const int ci = wid * 4 + i;
        const int rr = row0 + ci * 8 + l8;
        size_t a0;
        if (HMIN)
            a0 = (((size_t)(rr >> 11) * H_) * S_ + (rr & (S_ - 1))) * HD_ + colE;
        else
            a0 = (size_t)rr * DIM_ + colE;
        aptr[i] = A + a0;
        aldp[i] = As + ci * 512;
    }
    const u16* bptr[BCH]; u16* bldp[BCH];
#pragma unroll
    for (int i = 0; i < BCH; ++i) {
        const int ci = wid * BCH + i;
        const int rr = col0 + ci * 8 + l8;
        bptr[i] = Bt + (size_t)rr * DIM_ + colE;
        bldp[i] = Bs + ci * 512;
    }
    const size_t astep = HMIN ? (size_t)S_ * HD_ : 64;

    f32x4 acc[NM][NN];
#pragma unroll
    for (int m = 0; m < NM; ++m)
#pragma unroll
        for (int n = 0; n < NN; ++n) acc[m][n] = (f32x4){0.f, 0.f, 0.f, 0.f};

    for (int k0 = 0; k0 < DIM_; k0 += 64) {
        __syncthreads();   // previous frag reads done
#pragma unroll
        for (int i = 0; i < 4; ++i) gl16(aldp[i], aptr[i]);
#pragma unroll
        for (int i = 0; i < BCH; ++i) gl16(bldp[i], bptr[i]);
#pragma unroll
        for (int i = 0; i < 4; ++i) aptr[i] += astep;
#pragma unroll
        for (int i = 0; i < BCH; ++i) bptr[i] += 64;
        __syncthreads();   // loads drained

        s16x8 af[NM][2], bfr[NN][2];
#pragma unroll
        for (int m = 0; m < NM; ++m) {
            const int row = wr + m * 16 + l15;
#pragma unroll
            for (int kf = 0; kf < 2; ++kf)
                af[m][kf] = *(const s16x8*)&As[row * 64 +
                    (((kf * 64 + lg * 16) ^ ((l15 & 7) << 4)) >> 1)];
        }
#pragma unroll
        for (int n = 0; n < NN; ++n) {
            const int row = wc + n * 16 + l15;
#pragma unroll
            for (int kf = 0; kf < 2; ++kf)
                bfr[n][kf] = *(const s16x8*)&Bs[row * 64 +
                    (((kf * 64 + lg * 16) ^ ((l15 & 7) << 4)) >> 1)];
        }
        __builtin_amdgcn_s_setprio(1);
#pragma unroll
        for (int m = 0; m < NM; ++m)
#pragma unroll
            for (int n = 0; n < NN; ++n) {
                acc[m][n] = MFMA16(af[m][0], bfr[n][0], acc[m][n]);
                acc[m][n] = MFMA16(af[m][1], bfr[n][1], acc[m][n]);
            }
        __builtin_amdgcn_s_setprio(0);
    }

    // ---- epilogue
    if (EPI == 0) {
        u16* Y = (u16*)Yv;
        const int whichq = (col0 + wc) >> 10;          // wave-uniform
        if (whichq < 2) {
            // fused RoPE: pairs (n, n+2); out d = j and j+32
            const float sclw = (whichq == 0) ? CEXP : 1.0f;
#pragma unroll
            for (int n = 0; n < 2; ++n) {
                const int cc0 = col0 + wc + n * 16 + l15;
                const int j = n * 16 + l15;            // 0..31
                const float bv0 = bias[cc0];
                const float bv1 = bias[cc0 + 32];
                const int hh = (cc0 >> 6) & (H_ - 1);
#pragma unroll
                for (int m = 0; m < NM; ++m)
#pragma unroll
                    for (int r = 0; r < 4; ++r) {
                        const int rr = row0 + wr + m * 16 + lg * 4 + r;
                        const int b = rr >> 11, s = rr & (S_ - 1);
                        const float2 csv = cs[(s << 5) + j];
                        const float v0 = acc[m][n][r] + bv0;
                        const float v1 = acc[m][n + 2][r] + bv1;
                        const size_t base = (size_t)whichq * BHSD
                            + (((size_t)b * H_ + hh) * S_ + s) * HD_;
                        Y[base + j]      = f2bf((v0 * csv.x - v1 * csv.y) * sclw);
                        Y[base + j + 32] = f2bf((v0 * csv.y + v1 * csv.x) * sclw);
                    }
            }
        } else {
#pragma unroll
            for (int n = 0; n < NN; ++n) {
                const int cc = col0 + wc + n * 16 + l15;
                const float bv = bias[cc];
                const int hh = (cc >> 6) & (H_ - 1), d = cc & 63;
#pragma unroll
                for (int m = 0; m < NM; ++m)
#pragma unroll
                    for (int r = 0; r < 4; ++r) {
                        const int rr = row0 + wr + m * 16 + lg * 4 + r;
                        const int b = rr >> 11, s = rr & (S_ - 1);
                        // V^T with kv bits 2<->3 swapped (PV slot mapping)
                        const int sp = (s & ~12) | ((s & 4) << 1) | ((s & 8) >> 1);
                        Y[2 * BHSD + ((size_t)(b * H_ + hh) * HD_ + d) * S_ + sp] =
                            f2bf(acc[m][n][r] + bv);
                    }
            }
        }
    } else {
#pragma unroll
        for (int n = 0; n < NN; ++n) {
            const int cc = col0 + wc + n * 16 + l15;
            const float bv = bias[cc];
#pragma unroll
            for (int m = 0; m < NM; ++m)
#pragma unroll
                for (int r = 0; r < 4; ++r) {
                    const int rr = row0 + wr + m * 16 + lg * 4 + r;
                    ((float*)Yv)[(size_t)rr * DIM_ + cc] = acc[m][n][r] + bv;
                }
        }
    }
}

// ---------------------------------------------------------------------------
// Causal flash attention, MFMA32 + kv-split-2, max-free softmax.
// Block = 64 q rows, 4 waves: wave (wq = w&1, wk = w>>1): q rows
// qt*64 + wq*32 .. +31, kv strip wk*32 .. +31 of each 64-kv tile.
// No two waves read the same LDS bytes -> LDS read traffic halves vs the
// 16-row MFMA16 design. Partials are additive (max-free); merged via a
// fixed-role LDS handoff (wk1 writes, barrier, wk0 combines) - no atomics.
// Swapped QK^T (crow=(r&3)+8*(r>>2)+4h); V^T bit2<->3-permuted so PV
// A-fragments are lane-local. Grid (32 bh FAST, 32 y band-balanced) = 1024
// blocks, 32 KB LDS -> 4 co-resident blocks/CU. Output in place into Q.
// ---------------------------------------------------------------------------
__global__ __launch_bounds__(256, 4) void attn32(
    u16* __restrict__ Q, const u16* __restrict__ K, const u16* __restrict__ VT)
{
    const int bh = blockIdx.x;
    const int y  = blockIdx.y;                // 0..31
    const int a = y >> 3, r_ = y & 7;
    const int qt = (a == 0) ? (31 - r_) : (a == 1) ? (16 + r_)
                 : (a == 2) ? (15 - r_) : r_;   // band-balanced bijection
    const int nsteps = qt + 1;

    u16* Qg = Q + (size_t)bh * S_ * HD_;
    const u16* Kg = K + (size_t)bh * S_ * HD_;
    const u16* Vg = VT + (size_t)bh * HD_ * S_;   // bit2<->3-permuted [64][2048]

    __shared__ u16 Ks[2][64 * 64];   // 2 x 8 KB (reused as merge O buffer)
    __shared__ u16 Vs[2][64 * 64];   // 2 x 8 KB (reused as merge l buffer)

    const int tid = threadIdx.x;
    const int w = tid >> 6, lane = tid & 63;
    const int wq = w & 1, wk = w >> 1;
    const int l31 = lane & 31, h = lane >> 5;
    const int swz = l31 & 7;
    const int q0 = qt * 64 + wq * 32;
    const int krow = wk * 32 + l31;           // K LDS row for QK^T A-operand

    // staging: per wave 2 K-chunks + 2 V-chunks (8 rows x 64 cols each)
    const int crw = lane >> 3, cslt = lane & 7;
    auto stage = [&](int bufi, int j0) {
#pragma unroll
        for (int i = 0; i < 2; ++i) {
            const int c = w * 2 + i;                  // chunk 0..7
            const int row = c * 8 + crw;              // 0..63
            const int soff = ((cslt ^ (row & 7)) << 3);
            gl16(&Ks[bufi][c * 512], Kg + (size_t)(j0 + row) * HD_ + soff);
            gl16(&Vs[bufi][c * 512], Vg + (size_t)row * S_ + j0 + soff);
        }
    };

    // Q B-fragments: rows q0 + l31, k-slice ks*16 + h*8 (pre-scaled by CEXP)
    s16x8 qf[4];
    {
        const u16* qrow = Qg + (size_t)(q0 + l31) * HD_ + h * 8;
#pragma unroll
        for (int ks = 0; ks < 4; ++ks)
            qf[ks] = *(const s16x8*)(qrow + ks * 16);
    }

    f32x16 o0, o1;
#pragma unroll
    for (int r = 0; r < 16; ++r) { o0[r] = 0.f; o1[r] = 0.f; }
    float lI = 0.f;

    stage(0, 0);
    __syncthreads();

    int buf = 0;
    for (int t = 0; t < nsteps; ++t) {
        if (t + 1 < nsteps) stage(buf ^ 1, (t + 1) * 64);   // prefetch

        if (t < qt || wk <= wq) {             // wave-uniform masked-strip skip
            const u16* Kb = Ks[buf];
            const u16* Vb = Vs[buf];

            // ---- swapped QK^T: s[r] = S[kv=t*64+wk*32+crow(r,h)][q=q0+l31]
            f32x16 sc;
#pragma unroll
            for (int r = 0; r < 16; ++r) sc[r] = 0.f;
            __builtin_amdgcn_s_setprio(1);
#pragma unroll
            for (int ks = 0; ks < 4; ++ks) {
                const s16x8 kf = *(const s16x8*)&Kb[krow * 64 +
                    ((((ks << 1) | h) ^ swz) << 3)];
                sc = MFMA32(kf, qf[ks], sc);
            }
            __builtin_amdgcn_s_setprio(0);

            if (t == qt && wk == wq) {        // diagonal strip: element mask
#pragma unroll
                for (int r = 0; r < 16; ++r) {
                    const int cr = (r & 3) + 8 * (r >> 2) + 4 * h;
                    if (cr > l31) sc[r] = -1e30f;
                }
            }

            // ---- max-free softmax: p = exp2(s); masked -> 0
            float p[16];
            float ps = 0.f;
#pragma unroll
            for (int r = 0; r < 16; ++r) {
                p[r] = __builtin_amdgcn_exp2f(sc[r]);
                ps += p[r];
            }
            ps += __shfl_xor(ps, 32);         // combine h halves: l per q=l31
            lI += ps;

            // ---- PV: lane-local A-frags (bit2<->3-permuted V^T)
            __builtin_amdgcn_s_setprio(1);
#pragma unroll
            for (int m = 0; m < 2; ++m) {     // K=16 chunk within strip
                union { s16x8 v; u32 w4[4]; } pa;
#pragma unroll
                for (int q2 = 0; q2 < 4; ++q2)
                    pa.w4[q2] = cvt_pk_bf16(p[m * 8 + q2 * 2],
                                            p[m * 8 + q2 * 2 + 1]);
                const int sl = ((wk * 4 + m * 2 + h) ^ swz) << 3;
                const s16x8 v0 = *(const s16x8*)&Vb[l31 * 64 + sl];
                const s16x8 v1 = *(const s16x8*)&Vb[(32 + l31) * 64 + sl];
                o0 = MFMA32(pa.v, v0, o0);
                o1 = MFMA32(pa.v, v1, o1);
            }
            __builtin_amdgcn_s_setprio(0);
        }

        __syncthreads();   // drains prefetch; buffer handoff
        buf ^= 1;
    }

    // ---- kv-split merge: wk1 writes partials to LDS (reuse Ks/Vs), barrier,
    //      wk0 combines, normalizes, writes in place into Q. Fixed roles ->
    //      deterministic, no atomics/fences.
    u16* Om = &Ks[0][0];                      // [wq][32 q][64 d] bf16 = 8 KB
    float* Lm = (float*)&Vs[0][0];            // [wq][32 q] f32
    if (wk == 1) {
#pragma unroll
        for (int r = 0; r < 16; ++r) {
            const int cr = (r & 3) + 8 * (r >> 2) + 4 * h;
            Om[(wq * 32 + cr) * 64 + l31]      = f2bf(o0[r]);
            Om[(wq * 32 + cr) * 64 + 32 + l31] = f2bf(o1[r]);
        }
        if (lane < 32) Lm[wq * 32 + l31] = lI;
    }
    __syncthreads();
    if (wk == 0) {
        const float il = 1.f / (lI + Lm[wq * 32 + l31]);   // l for q = l31
#pragma unroll
        for (int r = 0; r < 16; ++r) {
            const int cr = (r & 3) + 8 * (r >> 2) + 4 * h;
            const float ilr = __shfl(il, cr);              // lane cr holds q=cr
            u16* orow = Qg + (size_t)(q0 + cr) * HD_;
            const float a0 = o0[r] + bf2f(Om[(wq * 32 + cr) * 64 + l31]);
            const float a1 = o1[r] + bf2f(Om[(wq * 32 + cr) * 64 + 32 + l31]);
            orow[l31]      = f2bf(a0 * ilr);
            orow[32 + l31] = f2bf(a1 * ilr);
        }
    }
}

// ---------------------------------------------------------------------------
extern "C" void kernel_launch(void* const* d_in, const int* in_sizes, int n_in,
                              void* d_out, int out_size, void* d_ws, size_t ws_size,
                              hipStream_t stream)
{
    (void)in_sizes; (void)n_in; (void)out_size; (void)ws_size;
    const float* x     = (const float*)d_in[0];
    const float* theta = (const float*)d_in[2];
    const float* Wq    = (const float*)d_in[3];
    const float* bq    = (const float*)d_in[4];
    const float* Wk    = (const float*)d_in[5];
    const float* bk    = (const float*)d_in[6];
    const float* Wv    = (const float*)d_in[7];
    const float* bv    = (const float*)d_in[8];
    const float* Wo    = (const float*)d_in[9];
    const float* bo    = (const float*)d_in[10];
    float* out = (float*)d_out;

    // ws (u16): xb 4M | wtq|wtk|wtv 3M | wto 1M | q 4M | k 4M | VT 4M |
    //           bias3 (3072 f32, padded to 4096) | cs table (2048x32 float2)
    u16* xb  = (u16*)d_ws;
    u16* wtq = xb + (size_t)BS_ * DIM_;
    u16* wtk = wtq + (size_t)DIM_ * DIM_;
    u16* wtv = wtk + (size_t)DIM_ * DIM_;
    u16* wto = wtv + (size_t)DIM_ * DIM_;
    u16* qws = wto + (size_t)DIM_ * DIM_;
    u16* kws = qws + BHSD;
    u16* vtw = kws + BHSD;
    float* bias3 = (float*)(vtw + BHSD);
    float2* cs = (float2*)(bias3 + 4096);

    // fused prep: cvt_x | wtrans(+perm) | cos/sin table | bias concat(+perm)
    prep<<<dim3(6412), dim3(256), 0, stream>>>(
        x, xb, Wq, Wk, Wv, Wo, wtq, wtk, wtv, wto, bq, bk, bv, bias3, theta, cs);

    // fused QKV projection: q,k rope'd head-major; V transposed+bit-permuted
    gemm_mfma<128, 0, 0><<<dim3(32, 24), dim3(256), 0, stream>>>(
        xb, wtq, bias3, qws, cs);

    // MFMA32 kv-split attention: 1024 co-resident blocks, halved LDS traffic
    attn32<<<dim3(32, 32), dim3(256), 0, stream>>>(qws, kws, vtw);

    // output projection (head-major A in, fp32 row-major out)
    gemm_mfma<64, 1, 1><<<dim3(32, 16), dim3(256), 0, stream>>>(
        qws, wto, bo, out, cs);
}